// Round 2
// baseline (195.949 us; speedup 1.0000x reference)
//
#include <hip/hip_runtime.h>
#include <cstdint>

#define P_N 65536
#define G_N 2048
#define SEGS 4
#define GSEG (G_N / SEGS)      // 512 gaussians per segment
#define PPB 64                 // points per block
#define L2E 1.4426950408889634f

#if __has_builtin(__builtin_amdgcn_exp2f)
#define EXP2F __builtin_amdgcn_exp2f
#else
#define EXP2F exp2f
#endif

// ws layout: int flag at byte 0 (1 => inside stored as 1-byte bool, 0 => int32)
//            params start at float offset 64: 16 floats per gaussian:
//            [0..8]  M row-major, M = sqrt(L2E/2) * diag(1/s) * R^T
//            [9..11] mu
//            [12]    lw = log2(sigmoid(w)*sigmoid(v))

__device__ __forceinline__ float sigmoidf(float x) {
    return 1.0f / (1.0f + expf(-x));
}

__global__ __launch_bounds__(256) void precompute_kernel(
        const float* __restrict__ xyz,
        const float* __restrict__ weight,
        const float* __restrict__ scaling,
        const float* __restrict__ rotation,
        const float* __restrict__ values,
        const uint8_t* __restrict__ inside_raw,
        float* __restrict__ ws) {
    // ---- inside-dtype detection (block 0 only) ----
    if (blockIdx.x == 0) {
        __shared__ int s_nz;
        if (threadIdx.x == 0) s_nz = 0;
        __syncthreads();
        int nz = 0;
        for (int i = threadIdx.x; i < 4096; i += blockDim.x) {
            if ((i & 3) != 0 && inside_raw[i] != 0) nz = 1;
        }
        if (nz) atomicOr(&s_nz, 1);
        __syncthreads();
        if (threadIdx.x == 0) ((int*)ws)[0] = s_nz;
    }

    int g = blockIdx.x * blockDim.x + threadIdx.x;
    if (g >= G_N) return;

    // capped scales
    float s0 = expf(scaling[3 * g + 0]);
    float s1 = expf(scaling[3 * g + 1]);
    float s2 = expf(scaling[3 * g + 2]);
    float r = sqrtf(s0 * s0 + s1 * s1 + s2 * s2) + 1e-8f;
    float r_soft = 0.02f * tanhf(r / 0.02f);
    float f = r_soft / r;
    s0 *= f; s1 *= f; s2 *= f;

    // quaternion -> rotation matrix
    float qw = rotation[4 * g + 0];
    float qx = rotation[4 * g + 1];
    float qy = rotation[4 * g + 2];
    float qz = rotation[4 * g + 3];
    float qn = sqrtf(qw * qw + qx * qx + qy * qy + qz * qz) + 1e-12f;
    qw /= qn; qx /= qn; qy /= qn; qz /= qn;
    float r00 = 1.0f - 2.0f * (qy * qy + qz * qz);
    float r01 = 2.0f * (qx * qy - qw * qz);
    float r02 = 2.0f * (qx * qz + qw * qy);
    float r10 = 2.0f * (qx * qy + qw * qz);
    float r11 = 1.0f - 2.0f * (qx * qx + qz * qz);
    float r12 = 2.0f * (qy * qz - qw * qx);
    float r20 = 2.0f * (qx * qz - qw * qy);
    float r21 = 2.0f * (qy * qz + qw * qx);
    float r22 = 1.0f - 2.0f * (qx * qx + qy * qy);

    // M = k * diag(1/s) * R^T, k = sqrt(L2E/2)
    // => power*L2E = -||M (x-mu)||^2 ; M[i][j] = k/s_i * R[j][i]
    const float k = 0.84932180028801904f;  // sqrt(ln2e... ) = sqrt(L2E*0.5)
    float k0 = k / s0, k1 = k / s1, k2 = k / s2;

    float wv = sigmoidf(weight[g]) * sigmoidf(values[g]);

    float* c = ws + 64 + (size_t)g * 16;
    c[0] = k0 * r00; c[1] = k0 * r10; c[2] = k0 * r20;
    c[3] = k1 * r01; c[4] = k1 * r11; c[5] = k1 * r21;
    c[6] = k2 * r02; c[7] = k2 * r12; c[8] = k2 * r22;
    c[9]  = xyz[3 * g + 0];
    c[10] = xyz[3 * g + 1];
    c[11] = xyz[3 * g + 2];
    c[12] = log2f(wv);
    c[13] = 0.0f; c[14] = 0.0f; c[15] = 0.0f;
}

__global__ __launch_bounds__(256) void eval_kernel(
        const float* __restrict__ x,
        const float* __restrict__ ws,
        const void* __restrict__ inside,
        float* __restrict__ out) {
    const float* params = ws + 64;
    const int mode = ((const int*)ws)[0];

    const int lp  = threadIdx.x & 63;
    const int seg = threadIdx.x >> 6;
    const int p   = blockIdx.x * PPB + lp;

    float X = (x[3 * p + 0] + 1.0f) * 0.5f;
    float Y = (x[3 * p + 1] + 1.0f) * 0.5f;
    float Z = (x[3 * p + 2] + 1.0f) * 0.5f;

    const float* cp = params + seg * GSEG * 16;
    float acc0 = 0.0f, acc1 = 0.0f;

#pragma unroll 8
    for (int g = 0; g < GSEG; ++g) {
        const float* c = cp + g * 16;
        float d0 = X - c[9];
        float d1 = Y - c[10];
        float d2 = Z - c[11];
        float u0 = c[0] * d0; u0 = fmaf(c[1], d1, u0); u0 = fmaf(c[2], d2, u0);
        float u1 = c[3] * d0; u1 = fmaf(c[4], d1, u1); u1 = fmaf(c[5], d2, u1);
        float u2 = c[6] * d0; u2 = fmaf(c[7], d1, u2); u2 = fmaf(c[8], d2, u2);
        float t = fmaf(-u0, u0, c[12]);
        t = fmaf(-u1, u1, t);
        t = fmaf(-u2, u2, t);
        float e = EXP2F(t);
        if (g & 1) acc1 += e; else acc0 += e;
    }

    __shared__ float part[SEGS][PPB];
    part[seg][lp] = acc0 + acc1;
    __syncthreads();

    if (seg == 0) {
        float y = part[0][lp] + part[1][lp] + part[2][lp] + part[3][lp];
        bool m = mode ? (((const uint8_t*)inside)[p] != 0)
                      : (((const int*)inside)[p] != 0);
        out[p] = m ? y : 0.0f;
    }
}

extern "C" void kernel_launch(void* const* d_in, const int* in_sizes, int n_in,
                              void* d_out, int out_size, void* d_ws, size_t ws_size,
                              hipStream_t stream) {
    const float* x        = (const float*)d_in[0];
    const float* xyz      = (const float*)d_in[1];
    const float* weight   = (const float*)d_in[2];
    const float* scaling  = (const float*)d_in[3];
    const float* rotation = (const float*)d_in[4];
    const float* values   = (const float*)d_in[5];
    const void*  inside   = d_in[6];

    float* ws  = (float*)d_ws;
    float* out = (float*)d_out;

    // params need 256 B header + G*16 floats
    if (ws_size < (size_t)(256 + G_N * 16 * 4)) return;

    precompute_kernel<<<(G_N + 255) / 256, 256, 0, stream>>>(
        xyz, weight, scaling, rotation, values, (const uint8_t*)inside, ws);

    eval_kernel<<<P_N / PPB, 256, 0, stream>>>(x, ws, inside, out);
}

// Round 3
// 88.806 us; speedup vs baseline: 2.2065x; 2.2065x over previous
//
#include <hip/hip_runtime.h>
#include <cstdint>

#define P_N 65536
#define G_N 2048
#define SEGS 4
#define GSEG (G_N / SEGS)      // 512 gaussians per segment
#define PPB 64                 // points per block
#define L2E 1.4426950408889634f

#if __has_builtin(__builtin_amdgcn_exp2f)
#define EXP2F __builtin_amdgcn_exp2f
#else
#define EXP2F exp2f
#endif

// ws layout: int flag at byte 0 (1 => inside stored as 1-byte bool, 0 => int32)
//            params start at float offset 64: 16 floats per gaussian:
//            [0..8]  M row-major, M = sqrt(L2E/2) * diag(1/s) * R^T
//            [9..11] nb = -(M·mu)   (so u = M·x + nb, no per-pair subtract)
//            [12]    lw = log2(sigmoid(w)*sigmoid(v))

__device__ __forceinline__ float sigmoidf(float x) {
    return 1.0f / (1.0f + expf(-x));
}

__global__ __launch_bounds__(256) void precompute_kernel(
        const float* __restrict__ xyz,
        const float* __restrict__ weight,
        const float* __restrict__ scaling,
        const float* __restrict__ rotation,
        const float* __restrict__ values,
        const uint8_t* __restrict__ inside_raw,
        float* __restrict__ ws) {
    // ---- inside-dtype detection (block 0 only) ----
    if (blockIdx.x == 0) {
        __shared__ int s_nz;
        if (threadIdx.x == 0) s_nz = 0;
        __syncthreads();
        int nz = 0;
        for (int i = threadIdx.x; i < 4096; i += blockDim.x) {
            if ((i & 3) != 0 && inside_raw[i] != 0) nz = 1;
        }
        if (nz) atomicOr(&s_nz, 1);
        __syncthreads();
        if (threadIdx.x == 0) ((int*)ws)[0] = s_nz;
    }

    int g = blockIdx.x * blockDim.x + threadIdx.x;
    if (g >= G_N) return;

    // capped scales
    float s0 = expf(scaling[3 * g + 0]);
    float s1 = expf(scaling[3 * g + 1]);
    float s2 = expf(scaling[3 * g + 2]);
    float r = sqrtf(s0 * s0 + s1 * s1 + s2 * s2) + 1e-8f;
    float r_soft = 0.02f * tanhf(r / 0.02f);
    float f = r_soft / r;
    s0 *= f; s1 *= f; s2 *= f;

    // quaternion -> rotation matrix
    float qw = rotation[4 * g + 0];
    float qx = rotation[4 * g + 1];
    float qy = rotation[4 * g + 2];
    float qz = rotation[4 * g + 3];
    float qn = sqrtf(qw * qw + qx * qx + qy * qy + qz * qz) + 1e-12f;
    qw /= qn; qx /= qn; qy /= qn; qz /= qn;
    float r00 = 1.0f - 2.0f * (qy * qy + qz * qz);
    float r01 = 2.0f * (qx * qy - qw * qz);
    float r02 = 2.0f * (qx * qz + qw * qy);
    float r10 = 2.0f * (qx * qy + qw * qz);
    float r11 = 1.0f - 2.0f * (qx * qx + qz * qz);
    float r12 = 2.0f * (qy * qz - qw * qx);
    float r20 = 2.0f * (qx * qz - qw * qy);
    float r21 = 2.0f * (qy * qz + qw * qx);
    float r22 = 1.0f - 2.0f * (qx * qx + qy * qy);

    // M = k * diag(1/s) * R^T, k = sqrt(L2E*0.5)
    // power*L2E = -||M x + nb||^2 + lw, nb = -M·mu
    const float k = 0.84932180028801904f;
    float k0 = k / s0, k1 = k / s1, k2 = k / s2;

    float m00 = k0 * r00, m01 = k0 * r10, m02 = k0 * r20;
    float m10 = k1 * r01, m11 = k1 * r11, m12 = k1 * r21;
    float m20 = k2 * r02, m21 = k2 * r12, m22 = k2 * r22;

    float mx = xyz[3 * g + 0], my = xyz[3 * g + 1], mz = xyz[3 * g + 2];

    float wv = sigmoidf(weight[g]) * sigmoidf(values[g]);

    float* c = ws + 64 + (size_t)g * 16;
    c[0] = m00; c[1] = m01; c[2] = m02;
    c[3] = m10; c[4] = m11; c[5] = m12;
    c[6] = m20; c[7] = m21; c[8] = m22;
    c[9]  = -(m00 * mx + m01 * my + m02 * mz);
    c[10] = -(m10 * mx + m11 * my + m12 * mz);
    c[11] = -(m20 * mx + m21 * my + m22 * mz);
    c[12] = log2f(wv);
    c[13] = 0.0f; c[14] = 0.0f; c[15] = 0.0f;
}

__global__ __launch_bounds__(256) void eval_kernel(
        const float* __restrict__ x,
        const float* __restrict__ ws,
        const void* __restrict__ inside,
        float* __restrict__ out) {
    const float* params = ws + 64;
    const int mode = ((const int*)ws)[0];

    const int lp  = threadIdx.x & 63;
    // readfirstlane makes seg PROVABLY wave-uniform -> parameter loads
    // become s_load (SMEM pipe), off the VMEM/VALU critical path.
    const int seg = __builtin_amdgcn_readfirstlane(threadIdx.x >> 6);
    const int p   = blockIdx.x * PPB + lp;

    float X = (x[3 * p + 0] + 1.0f) * 0.5f;
    float Y = (x[3 * p + 1] + 1.0f) * 0.5f;
    float Z = (x[3 * p + 2] + 1.0f) * 0.5f;

    const float* cp = params + (size_t)seg * GSEG * 16;
    float acc0 = 0.0f, acc1 = 0.0f;

#pragma unroll 4
    for (int g = 0; g < GSEG; ++g) {
        const float* c = cp + g * 16;
        float u0 = fmaf(c[0], X, fmaf(c[1], Y, fmaf(c[2], Z, c[9])));
        float u1 = fmaf(c[3], X, fmaf(c[4], Y, fmaf(c[5], Z, c[10])));
        float u2 = fmaf(c[6], X, fmaf(c[7], Y, fmaf(c[8], Z, c[11])));
        float t = fmaf(-u0, u0, c[12]);
        t = fmaf(-u1, u1, t);
        t = fmaf(-u2, u2, t);
        float e = EXP2F(t);
        if (g & 1) acc1 += e; else acc0 += e;
    }

    __shared__ float part[SEGS][PPB];
    part[seg][lp] = acc0 + acc1;
    __syncthreads();

    if (seg == 0) {
        float y = part[0][lp] + part[1][lp] + part[2][lp] + part[3][lp];
        bool m = mode ? (((const uint8_t*)inside)[p] != 0)
                      : (((const int*)inside)[p] != 0);
        out[p] = m ? y : 0.0f;
    }
}

extern "C" void kernel_launch(void* const* d_in, const int* in_sizes, int n_in,
                              void* d_out, int out_size, void* d_ws, size_t ws_size,
                              hipStream_t stream) {
    const float* x        = (const float*)d_in[0];
    const float* xyz      = (const float*)d_in[1];
    const float* weight   = (const float*)d_in[2];
    const float* scaling  = (const float*)d_in[3];
    const float* rotation = (const float*)d_in[4];
    const float* values   = (const float*)d_in[5];
    const void*  inside   = d_in[6];

    float* ws  = (float*)d_ws;
    float* out = (float*)d_out;

    // params need 256 B header + G*16 floats
    if (ws_size < (size_t)(256 + G_N * 16 * 4)) return;

    precompute_kernel<<<(G_N + 255) / 256, 256, 0, stream>>>(
        xyz, weight, scaling, rotation, values, (const uint8_t*)inside, ws);

    eval_kernel<<<P_N / PPB, 256, 0, stream>>>(x, ws, inside, out);
}

// Round 4
// 77.162 us; speedup vs baseline: 2.5394x; 1.1509x over previous
//
#include <hip/hip_runtime.h>
#include <cstdint>

#define P_N 65536
#define G_N 2048
#define SEGS 8
#define GPW (G_N / SEGS)       // 256 gaussians per wave
#define PPB 64                 // points per block (one wave's worth)
#define L2E 1.4426950408889634f

#if __has_builtin(__builtin_amdgcn_exp2f)
#define EXP2F __builtin_amdgcn_exp2f
#else
#define EXP2F exp2f
#endif

// ws layout: int flag at byte 0 (1 => inside stored as 1-byte bool, 0 => int32)
//            params at float offset 64: 16 floats per gaussian (G_N+2 records,
//            2 pad records so the rolling prefetch never branches):
//            [0..8]  M row-major, M = sqrt(L2E/2) * diag(1/s) * R^T
//            [9..11] nb = -(M·mu)   (u = M·x + nb)
//            [12]    lw = log2(sigmoid(w)*sigmoid(v))

__device__ __forceinline__ float sigmoidf(float x) {
    return 1.0f / (1.0f + expf(-x));
}

__global__ __launch_bounds__(256) void precompute_kernel(
        const float* __restrict__ xyz,
        const float* __restrict__ weight,
        const float* __restrict__ scaling,
        const float* __restrict__ rotation,
        const float* __restrict__ values,
        const uint8_t* __restrict__ inside_raw,
        float* __restrict__ ws) {
    // ---- inside-dtype detection + pad records (block 0 only) ----
    if (blockIdx.x == 0) {
        __shared__ int s_nz;
        if (threadIdx.x == 0) s_nz = 0;
        __syncthreads();
        int nz = 0;
        for (int i = threadIdx.x; i < 4096; i += blockDim.x) {
            if ((i & 3) != 0 && inside_raw[i] != 0) nz = 1;
        }
        if (nz) atomicOr(&s_nz, 1);
        __syncthreads();
        if (threadIdx.x == 0) ((int*)ws)[0] = s_nz;
        if (threadIdx.x < 32) {  // zero the 2 pad records
            ws[64 + (size_t)G_N * 16 + threadIdx.x] = 0.0f;
        }
    }

    int g = blockIdx.x * blockDim.x + threadIdx.x;
    if (g >= G_N) return;

    // capped scales
    float s0 = expf(scaling[3 * g + 0]);
    float s1 = expf(scaling[3 * g + 1]);
    float s2 = expf(scaling[3 * g + 2]);
    float r = sqrtf(s0 * s0 + s1 * s1 + s2 * s2) + 1e-8f;
    float r_soft = 0.02f * tanhf(r / 0.02f);
    float f = r_soft / r;
    s0 *= f; s1 *= f; s2 *= f;

    // quaternion -> rotation matrix
    float qw = rotation[4 * g + 0];
    float qx = rotation[4 * g + 1];
    float qy = rotation[4 * g + 2];
    float qz = rotation[4 * g + 3];
    float qn = sqrtf(qw * qw + qx * qx + qy * qy + qz * qz) + 1e-12f;
    qw /= qn; qx /= qn; qy /= qn; qz /= qn;
    float r00 = 1.0f - 2.0f * (qy * qy + qz * qz);
    float r01 = 2.0f * (qx * qy - qw * qz);
    float r02 = 2.0f * (qx * qz + qw * qy);
    float r10 = 2.0f * (qx * qy + qw * qz);
    float r11 = 1.0f - 2.0f * (qx * qx + qz * qz);
    float r12 = 2.0f * (qy * qz - qw * qx);
    float r20 = 2.0f * (qx * qz - qw * qy);
    float r21 = 2.0f * (qy * qz + qw * qx);
    float r22 = 1.0f - 2.0f * (qx * qx + qy * qy);

    // M = k * diag(1/s) * R^T, k = sqrt(L2E*0.5)
    // power*L2E = -||M x + nb||^2 + lw
    const float k = 0.84932180028801904f;
    float k0 = k / s0, k1 = k / s1, k2 = k / s2;

    float m00 = k0 * r00, m01 = k0 * r10, m02 = k0 * r20;
    float m10 = k1 * r01, m11 = k1 * r11, m12 = k1 * r21;
    float m20 = k2 * r02, m21 = k2 * r12, m22 = k2 * r22;

    float mx = xyz[3 * g + 0], my = xyz[3 * g + 1], mz = xyz[3 * g + 2];
    float wv = sigmoidf(weight[g]) * sigmoidf(values[g]);

    float* c = ws + 64 + (size_t)g * 16;
    c[0] = m00; c[1] = m01; c[2] = m02;
    c[3] = m10; c[4] = m11; c[5] = m12;
    c[6] = m20; c[7] = m21; c[8] = m22;
    c[9]  = -(m00 * mx + m01 * my + m02 * mz);
    c[10] = -(m10 * mx + m11 * my + m12 * mz);
    c[11] = -(m20 * mx + m21 * my + m22 * mz);
    c[12] = log2f(wv);
    c[13] = 0.0f; c[14] = 0.0f; c[15] = 0.0f;
}

__global__ __launch_bounds__(512) void eval_kernel(
        const float* __restrict__ x,
        const float* __restrict__ ws,
        const void* __restrict__ inside,
        float* __restrict__ out) {
    const float* params = ws + 64;
    const int mode = ((const int*)ws)[0];

    const int lp  = threadIdx.x & 63;
    // readfirstlane: provably wave-uniform -> param loads stay on SMEM pipe
    const int seg = __builtin_amdgcn_readfirstlane(threadIdx.x >> 6);
    const int p   = blockIdx.x * PPB + lp;

    float X = (x[3 * p + 0] + 1.0f) * 0.5f;
    float Y = (x[3 * p + 1] + 1.0f) * 0.5f;
    float Z = (x[3 * p + 2] + 1.0f) * 0.5f;

    const float4* c4 = (const float4*)(params + (size_t)seg * GPW * 16);
    float acc0 = 0.0f, acc1 = 0.0f;

    // rolling prefetch: n* always holds the NEXT record's 16 floats
    float4 n0 = c4[0], n1 = c4[1], n2 = c4[2], n3 = c4[3];

#pragma unroll 1
    for (int g = 0; g < GPW; g += 2) {
        float4 a0 = n0, a1 = n1, a2 = n2, a3 = n3;
        {
            const float4* q = c4 + (size_t)(g + 1) * 4;
            n0 = q[0]; n1 = q[1]; n2 = q[2]; n3 = q[3];
        }
        float au0 = fmaf(a0.x, X, fmaf(a0.y, Y, fmaf(a0.z, Z, a2.y)));
        float au1 = fmaf(a0.w, X, fmaf(a1.x, Y, fmaf(a1.y, Z, a2.z)));
        float au2 = fmaf(a1.z, X, fmaf(a1.w, Y, fmaf(a2.x, Z, a2.w)));
        float at = fmaf(-au0, au0, a3.x);
        at = fmaf(-au1, au1, at);
        at = fmaf(-au2, au2, at);
        acc0 += EXP2F(at);

        float4 b0 = n0, b1 = n1, b2 = n2, b3 = n3;
        {
            const float4* q = c4 + (size_t)(g + 2) * 4;  // pad records cover tail
            n0 = q[0]; n1 = q[1]; n2 = q[2]; n3 = q[3];
        }
        float bu0 = fmaf(b0.x, X, fmaf(b0.y, Y, fmaf(b0.z, Z, b2.y)));
        float bu1 = fmaf(b0.w, X, fmaf(b1.x, Y, fmaf(b1.y, Z, b2.z)));
        float bu2 = fmaf(b1.z, X, fmaf(b1.w, Y, fmaf(b2.x, Z, b2.w)));
        float bt = fmaf(-bu0, bu0, b3.x);
        bt = fmaf(-bu1, bu1, bt);
        bt = fmaf(-bu2, bu2, bt);
        acc1 += EXP2F(bt);
    }

    __shared__ float part[SEGS][PPB];
    part[seg][lp] = acc0 + acc1;
    __syncthreads();

    if (threadIdx.x < PPB) {
        float y = 0.0f;
#pragma unroll
        for (int s = 0; s < SEGS; ++s) y += part[s][lp];
        bool m = mode ? (((const uint8_t*)inside)[p] != 0)
                      : (((const int*)inside)[p] != 0);
        out[p] = m ? y : 0.0f;
    }
}

extern "C" void kernel_launch(void* const* d_in, const int* in_sizes, int n_in,
                              void* d_out, int out_size, void* d_ws, size_t ws_size,
                              hipStream_t stream) {
    const float* x        = (const float*)d_in[0];
    const float* xyz      = (const float*)d_in[1];
    const float* weight   = (const float*)d_in[2];
    const float* scaling  = (const float*)d_in[3];
    const float* rotation = (const float*)d_in[4];
    const float* values   = (const float*)d_in[5];
    const void*  inside   = d_in[6];

    float* ws  = (float*)d_ws;
    float* out = (float*)d_out;

    // 256 B header + (G_N+2)*16 floats
    if (ws_size < (size_t)(256 + (G_N + 2) * 16 * 4)) return;

    precompute_kernel<<<(G_N + 255) / 256, 256, 0, stream>>>(
        xyz, weight, scaling, rotation, values, (const uint8_t*)inside, ws);

    eval_kernel<<<P_N / PPB, 512, 0, stream>>>(x, ws, inside, out);
}

// Round 5
// 67.375 us; speedup vs baseline: 2.9083x; 1.1453x over previous
//
#include <hip/hip_runtime.h>
#include <cstdint>

#define P_N 65536
#define G_N 2048
#define NSEG 32
#define GSEG (G_N / NSEG)      // 64 gaussians per segment
#define L2E 1.4426950408889634f

#if __has_builtin(__builtin_amdgcn_exp2f)
#define EXP2F __builtin_amdgcn_exp2f
#else
#define EXP2F exp2f
#endif

// ws layout: int flag at byte 0 (1 => inside stored as 1-byte bool, 0 => int32)
//            params at float offset 64: 16 floats per gaussian (G_N+2 records,
//            pad records so the rolling prefetch never branches):
//            [0..8]  M row-major, M = sqrt(L2E/2) * diag(1/s) * R^T
//            [9..11] nb = -(M·mu)   (u = M·x + nb)
//            [12]    lw = log2(sigmoid(w)*sigmoid(v))

__device__ __forceinline__ float sigmoidf(float x) {
    return 1.0f / (1.0f + expf(-x));
}

__global__ __launch_bounds__(256) void precompute_kernel(
        const float* __restrict__ xyz,
        const float* __restrict__ weight,
        const float* __restrict__ scaling,
        const float* __restrict__ rotation,
        const float* __restrict__ values,
        const uint8_t* __restrict__ inside_raw,
        float* __restrict__ ws) {
    // ---- inside-dtype detection + pad records (block 0 only) ----
    if (blockIdx.x == 0) {
        __shared__ int s_nz;
        if (threadIdx.x == 0) s_nz = 0;
        __syncthreads();
        int nz = 0;
        for (int i = threadIdx.x; i < 4096; i += blockDim.x) {
            if ((i & 3) != 0 && inside_raw[i] != 0) nz = 1;
        }
        if (nz) atomicOr(&s_nz, 1);
        __syncthreads();
        if (threadIdx.x == 0) ((int*)ws)[0] = s_nz;
        if (threadIdx.x < 32) {  // zero the 2 pad records
            ws[64 + (size_t)G_N * 16 + threadIdx.x] = 0.0f;
        }
    }

    int g = blockIdx.x * blockDim.x + threadIdx.x;
    if (g >= G_N) return;

    // capped scales
    float s0 = expf(scaling[3 * g + 0]);
    float s1 = expf(scaling[3 * g + 1]);
    float s2 = expf(scaling[3 * g + 2]);
    float r = sqrtf(s0 * s0 + s1 * s1 + s2 * s2) + 1e-8f;
    float r_soft = 0.02f * tanhf(r / 0.02f);
    float f = r_soft / r;
    s0 *= f; s1 *= f; s2 *= f;

    // quaternion -> rotation matrix
    float qw = rotation[4 * g + 0];
    float qx = rotation[4 * g + 1];
    float qy = rotation[4 * g + 2];
    float qz = rotation[4 * g + 3];
    float qn = sqrtf(qw * qw + qx * qx + qy * qy + qz * qz) + 1e-12f;
    qw /= qn; qx /= qn; qy /= qn; qz /= qn;
    float r00 = 1.0f - 2.0f * (qy * qy + qz * qz);
    float r01 = 2.0f * (qx * qy - qw * qz);
    float r02 = 2.0f * (qx * qz + qw * qy);
    float r10 = 2.0f * (qx * qy + qw * qz);
    float r11 = 1.0f - 2.0f * (qx * qx + qz * qz);
    float r12 = 2.0f * (qy * qz - qw * qx);
    float r20 = 2.0f * (qx * qz - qw * qy);
    float r21 = 2.0f * (qy * qz + qw * qx);
    float r22 = 1.0f - 2.0f * (qx * qx + qy * qy);

    // M = k * diag(1/s) * R^T, k = sqrt(L2E*0.5)
    // power*L2E = -||M x + nb||^2 + lw
    const float k = 0.84932180028801904f;
    float k0 = k / s0, k1 = k / s1, k2 = k / s2;

    float m00 = k0 * r00, m01 = k0 * r10, m02 = k0 * r20;
    float m10 = k1 * r01, m11 = k1 * r11, m12 = k1 * r21;
    float m20 = k2 * r02, m21 = k2 * r12, m22 = k2 * r22;

    float mx = xyz[3 * g + 0], my = xyz[3 * g + 1], mz = xyz[3 * g + 2];
    float wv = sigmoidf(weight[g]) * sigmoidf(values[g]);

    float* c = ws + 64 + (size_t)g * 16;
    c[0] = m00; c[1] = m01; c[2] = m02;
    c[3] = m10; c[4] = m11; c[5] = m12;
    c[6] = m20; c[7] = m21; c[8] = m22;
    c[9]  = -(m00 * mx + m01 * my + m02 * mz);
    c[10] = -(m10 * mx + m11 * my + m12 * mz);
    c[11] = -(m20 * mx + m21 * my + m22 * mz);
    c[12] = log2f(wv);
    c[13] = 0.0f; c[14] = 0.0f; c[15] = 0.0f;
}

// 4-point body for one record held in SGPR float4s r0..r3
#define GAUSS_POINT(r0, r1, r2, r3, Xk, Yk, Zk, acck)                         \
    {                                                                         \
        float u0 = fmaf(r0.x, Xk, fmaf(r0.y, Yk, fmaf(r0.z, Zk, r2.y)));      \
        float u1 = fmaf(r0.w, Xk, fmaf(r1.x, Yk, fmaf(r1.y, Zk, r2.z)));      \
        float u2 = fmaf(r1.z, Xk, fmaf(r1.w, Yk, fmaf(r2.x, Zk, r2.w)));      \
        float t  = fmaf(-u0, u0, r3.x);                                       \
        t = fmaf(-u1, u1, t);                                                 \
        t = fmaf(-u2, u2, t);                                                 \
        acck += EXP2F(t);                                                     \
    }

__global__ __launch_bounds__(256) void eval_kernel(
        const float* __restrict__ x,
        const float* __restrict__ ws,
        const void* __restrict__ inside,
        float* __restrict__ out) {
    const float* params = ws + 64;
    const int mode = ((const int*)ws)[0];

    const int lane = threadIdx.x & 63;
    // readfirstlane: provably wave-uniform -> param loads stay on SMEM pipe
    const int wv   = __builtin_amdgcn_readfirstlane(threadIdx.x >> 6);
    const int gwid = blockIdx.x * 4 + wv;
    const int pg   = gwid >> 5;          // 0..255  point group (256 points)
    const int seg  = gwid & 31;          // 0..31   gaussian segment (64 records)

    const int p0 = pg * 256 + lane;

    float X0 = (x[3 * (p0 +   0) + 0] + 1.0f) * 0.5f;
    float Y0 = (x[3 * (p0 +   0) + 1] + 1.0f) * 0.5f;
    float Z0 = (x[3 * (p0 +   0) + 2] + 1.0f) * 0.5f;
    float X1 = (x[3 * (p0 +  64) + 0] + 1.0f) * 0.5f;
    float Y1 = (x[3 * (p0 +  64) + 1] + 1.0f) * 0.5f;
    float Z1 = (x[3 * (p0 +  64) + 2] + 1.0f) * 0.5f;
    float X2 = (x[3 * (p0 + 128) + 0] + 1.0f) * 0.5f;
    float Y2 = (x[3 * (p0 + 128) + 1] + 1.0f) * 0.5f;
    float Z2 = (x[3 * (p0 + 128) + 2] + 1.0f) * 0.5f;
    float X3 = (x[3 * (p0 + 192) + 0] + 1.0f) * 0.5f;
    float Y3 = (x[3 * (p0 + 192) + 1] + 1.0f) * 0.5f;
    float Z3 = (x[3 * (p0 + 192) + 2] + 1.0f) * 0.5f;

    const float4* c4 = (const float4*)(params + (size_t)seg * GSEG * 16);
    float acc0 = 0.0f, acc1 = 0.0f, acc2 = 0.0f, acc3 = 0.0f;

    // rolling prefetch: n* holds the NEXT record
    float4 n0 = c4[0], n1 = c4[1], n2 = c4[2], n3 = c4[3];

#pragma unroll 1
    for (int g = 0; g < GSEG; g += 2) {
        float4 a0 = n0, a1 = n1, a2 = n2, a3 = n3;
        {
            const float4* q = c4 + (size_t)(g + 1) * 4;
            n0 = q[0]; n1 = q[1]; n2 = q[2]; n3 = q[3];
        }
        GAUSS_POINT(a0, a1, a2, a3, X0, Y0, Z0, acc0);
        GAUSS_POINT(a0, a1, a2, a3, X1, Y1, Z1, acc1);
        GAUSS_POINT(a0, a1, a2, a3, X2, Y2, Z2, acc2);
        GAUSS_POINT(a0, a1, a2, a3, X3, Y3, Z3, acc3);

        float4 b0 = n0, b1 = n1, b2 = n2, b3 = n3;
        {
            const float4* q = c4 + (size_t)(g + 2) * 4;  // pad records cover tail
            n0 = q[0]; n1 = q[1]; n2 = q[2]; n3 = q[3];
        }
        GAUSS_POINT(b0, b1, b2, b3, X0, Y0, Z0, acc0);
        GAUSS_POINT(b0, b1, b2, b3, X1, Y1, Z1, acc1);
        GAUSS_POINT(b0, b1, b2, b3, X2, Y2, Z2, acc2);
        GAUSS_POINT(b0, b1, b2, b3, X3, Y3, Z3, acc3);
    }

    // masked cross-block combine (out zeroed by hipMemsetAsync in launch)
    const uint8_t* ib = (const uint8_t*)inside;
    const int*     ii = (const int*)inside;
#pragma unroll
    for (int kk = 0; kk < 4; ++kk) {
        int p = p0 + 64 * kk;
        float a = (kk == 0) ? acc0 : (kk == 1) ? acc1 : (kk == 2) ? acc2 : acc3;
        bool m = mode ? (ib[p] != 0) : (ii[p] != 0);
        if (m) atomicAdd(&out[p], a);
    }
}

extern "C" void kernel_launch(void* const* d_in, const int* in_sizes, int n_in,
                              void* d_out, int out_size, void* d_ws, size_t ws_size,
                              hipStream_t stream) {
    const float* x        = (const float*)d_in[0];
    const float* xyz      = (const float*)d_in[1];
    const float* weight   = (const float*)d_in[2];
    const float* scaling  = (const float*)d_in[3];
    const float* rotation = (const float*)d_in[4];
    const float* values   = (const float*)d_in[5];
    const void*  inside   = d_in[6];

    float* ws  = (float*)d_ws;
    float* out = (float*)d_out;

    // 256 B header + (G_N+2)*16 floats
    if (ws_size < (size_t)(256 + (G_N + 2) * 16 * 4)) return;

    hipMemsetAsync(d_out, 0, (size_t)P_N * sizeof(float), stream);

    precompute_kernel<<<(G_N + 255) / 256, 256, 0, stream>>>(
        xyz, weight, scaling, rotation, values, (const uint8_t*)inside, ws);

    // 8192 waves = 100% of 256 CU x 32 waves
    eval_kernel<<<(P_N / 256) * (NSEG / 4), 256, 0, stream>>>(x, ws, inside, out);
}

// Round 6
// 58.355 us; speedup vs baseline: 3.3579x; 1.1546x over previous
//
#include <hip/hip_runtime.h>
#include <cstdint>

#define P_N 65536
#define G_N 2048
#define GSEG 64                // gaussians per wave-segment
#define L2E 1.4426950408889634f

#if __has_builtin(__builtin_amdgcn_exp2f)
#define EXP2F __builtin_amdgcn_exp2f
#else
#define EXP2F exp2f
#endif

// ws layout: int flag at byte 0 (1 => inside stored as 1-byte bool, 0 => int32)
//            params at float offset 64: 16 floats per gaussian (G_N+2 records,
//            pad records zeroed; pads are staged/prefetched but never used):
//            [0..8]  M row-major, M = sqrt(L2E/2) * diag(1/s) * R^T
//            [9..11] nb = -(M·mu)   (u = M·x + nb)
//            [12]    lw = log2(sigmoid(w)*sigmoid(v))

__device__ __forceinline__ float sigmoidf(float x) {
    return 1.0f / (1.0f + expf(-x));
}

__global__ __launch_bounds__(256) void precompute_kernel(
        const float* __restrict__ xyz,
        const float* __restrict__ weight,
        const float* __restrict__ scaling,
        const float* __restrict__ rotation,
        const float* __restrict__ values,
        const uint8_t* __restrict__ inside_raw,
        float* __restrict__ ws) {
    // ---- inside-dtype detection + pad records (block 0 only) ----
    if (blockIdx.x == 0) {
        __shared__ int s_nz;
        if (threadIdx.x == 0) s_nz = 0;
        __syncthreads();
        int nz = 0;
        for (int i = threadIdx.x; i < 4096; i += blockDim.x) {
            if ((i & 3) != 0 && inside_raw[i] != 0) nz = 1;
        }
        if (nz) atomicOr(&s_nz, 1);
        __syncthreads();
        if (threadIdx.x == 0) ((int*)ws)[0] = s_nz;
        if (threadIdx.x < 32) {  // zero the 2 pad records
            ws[64 + (size_t)G_N * 16 + threadIdx.x] = 0.0f;
        }
    }

    int g = blockIdx.x * blockDim.x + threadIdx.x;
    if (g >= G_N) return;

    // capped scales
    float s0 = expf(scaling[3 * g + 0]);
    float s1 = expf(scaling[3 * g + 1]);
    float s2 = expf(scaling[3 * g + 2]);
    float r = sqrtf(s0 * s0 + s1 * s1 + s2 * s2) + 1e-8f;
    float r_soft = 0.02f * tanhf(r / 0.02f);
    float f = r_soft / r;
    s0 *= f; s1 *= f; s2 *= f;

    // quaternion -> rotation matrix
    float qw = rotation[4 * g + 0];
    float qx = rotation[4 * g + 1];
    float qy = rotation[4 * g + 2];
    float qz = rotation[4 * g + 3];
    float qn = sqrtf(qw * qw + qx * qx + qy * qy + qz * qz) + 1e-12f;
    qw /= qn; qx /= qn; qy /= qn; qz /= qn;
    float r00 = 1.0f - 2.0f * (qy * qy + qz * qz);
    float r01 = 2.0f * (qx * qy - qw * qz);
    float r02 = 2.0f * (qx * qz + qw * qy);
    float r10 = 2.0f * (qx * qy + qw * qz);
    float r11 = 1.0f - 2.0f * (qx * qx + qz * qz);
    float r12 = 2.0f * (qy * qz - qw * qx);
    float r20 = 2.0f * (qx * qz - qw * qy);
    float r21 = 2.0f * (qy * qz + qw * qx);
    float r22 = 1.0f - 2.0f * (qx * qx + qy * qy);

    // M = k * diag(1/s) * R^T, k = sqrt(L2E*0.5)
    // power*L2E = -||M x + nb||^2 + lw
    const float k = 0.84932180028801904f;
    float k0 = k / s0, k1 = k / s1, k2 = k / s2;

    float m00 = k0 * r00, m01 = k0 * r10, m02 = k0 * r20;
    float m10 = k1 * r01, m11 = k1 * r11, m12 = k1 * r21;
    float m20 = k2 * r02, m21 = k2 * r12, m22 = k2 * r22;

    float mx = xyz[3 * g + 0], my = xyz[3 * g + 1], mz = xyz[3 * g + 2];
    float wv = sigmoidf(weight[g]) * sigmoidf(values[g]);

    float* c = ws + 64 + (size_t)g * 16;
    c[0] = m00; c[1] = m01; c[2] = m02;
    c[3] = m10; c[4] = m11; c[5] = m12;
    c[6] = m20; c[7] = m21; c[8] = m22;
    c[9]  = -(m00 * mx + m01 * my + m02 * mz);
    c[10] = -(m10 * mx + m11 * my + m12 * mz);
    c[11] = -(m20 * mx + m21 * my + m22 * mz);
    c[12] = log2f(wv);
    c[13] = 0.0f; c[14] = 0.0f; c[15] = 0.0f;
}

// one record (float4 r0..r3) applied to one point (Xk,Yk,Zk) -> acck
#define GAUSS_POINT(r0, r1, r2, r3, Xk, Yk, Zk, acck)                         \
    {                                                                         \
        float u0 = fmaf(r0.x, Xk, fmaf(r0.y, Yk, fmaf(r0.z, Zk, r2.y)));      \
        float u1 = fmaf(r0.w, Xk, fmaf(r1.x, Yk, fmaf(r1.y, Zk, r2.z)));      \
        float u2 = fmaf(r1.z, Xk, fmaf(r1.w, Yk, fmaf(r2.x, Zk, r2.w)));      \
        float t  = fmaf(-u0, u0, r3.x);                                       \
        t = fmaf(-u1, u1, t);                                                 \
        t = fmaf(-u2, u2, t);                                                 \
        acck += EXP2F(t);                                                     \
    }

#define GAUSS_REC4(r0, r1, r2, r3)                                           \
    GAUSS_POINT(r0, r1, r2, r3, X0, Y0, Z0, acc0);                            \
    GAUSS_POINT(r0, r1, r2, r3, X1, Y1, Z1, acc1);                            \
    GAUSS_POINT(r0, r1, r2, r3, X2, Y2, Z2, acc2);                            \
    GAUSS_POINT(r0, r1, r2, r3, X3, Y3, Z3, acc3);

// block = (point-group pg of 256 points) x (seg-quad of 4x64 gaussians)
// wave w processes segment segq*4+w for all 256 points (4 per lane)
// params are staged to LDS once; inner loop reads records via ds_read_b128
// (uniform address -> broadcast, in-order returns -> fine-grained lgkmcnt)
__global__ __launch_bounds__(256) void eval_kernel(
        const float* __restrict__ x,
        const float* __restrict__ ws,
        const void* __restrict__ inside,
        float* __restrict__ out) {
    __shared__ float4 spbuf[1028];   // 257 records: 4 segs + 1 overread pad
    const float* params = ws + 64;
    const int mode = ((const int*)ws)[0];

    const int tid  = threadIdx.x;
    const int lane = tid & 63;
    const int w    = tid >> 6;
    const int segq = blockIdx.x & 7;    // 0..7  (seg-quad)
    const int pg   = blockIdx.x >> 3;   // 0..255 (point group)

    // stage 257 records (16.4 KB) to LDS, coalesced
    const float4* src = (const float4*)(params + (size_t)segq * 256 * 16);
#pragma unroll
    for (int i = 0; i < 4; ++i) spbuf[tid + 256 * i] = src[tid + 256 * i];
    if (tid < 4) spbuf[1024 + tid] = src[1024 + tid];

    const int p0 = pg * 256 + lane;
    float X0 = (x[3 * (p0 +   0) + 0] + 1.0f) * 0.5f;
    float Y0 = (x[3 * (p0 +   0) + 1] + 1.0f) * 0.5f;
    float Z0 = (x[3 * (p0 +   0) + 2] + 1.0f) * 0.5f;
    float X1 = (x[3 * (p0 +  64) + 0] + 1.0f) * 0.5f;
    float Y1 = (x[3 * (p0 +  64) + 1] + 1.0f) * 0.5f;
    float Z1 = (x[3 * (p0 +  64) + 2] + 1.0f) * 0.5f;
    float X2 = (x[3 * (p0 + 128) + 0] + 1.0f) * 0.5f;
    float Y2 = (x[3 * (p0 + 128) + 1] + 1.0f) * 0.5f;
    float Z2 = (x[3 * (p0 + 128) + 2] + 1.0f) * 0.5f;
    float X3 = (x[3 * (p0 + 192) + 0] + 1.0f) * 0.5f;
    float Y3 = (x[3 * (p0 + 192) + 1] + 1.0f) * 0.5f;
    float Z3 = (x[3 * (p0 + 192) + 2] + 1.0f) * 0.5f;

    __syncthreads();

    const float4* sp = spbuf + (size_t)w * 256;  // this wave's 64 records
    float acc0 = 0.0f, acc1 = 0.0f, acc2 = 0.0f, acc3 = 0.0f;

    // register ping-pong: A holds record g, B holds record g+1
    float4 A0 = sp[0], A1 = sp[1], A2 = sp[2], A3 = sp[3];
    float4 B0, B1, B2, B3;

#pragma unroll 1
    for (int g = 0; g < GSEG; g += 2) {
        const float4* q = sp + (size_t)(g + 1) * 4;
        B0 = q[0]; B1 = q[1]; B2 = q[2]; B3 = q[3];
        GAUSS_REC4(A0, A1, A2, A3);
        q = sp + (size_t)(g + 2) * 4;      // overread pad at tail, never used
        A0 = q[0]; A1 = q[1]; A2 = q[2]; A3 = q[3];
        GAUSS_REC4(B0, B1, B2, B3);
    }

    // block-local combine (alias partials onto the param buffer)
    __syncthreads();
    float* part = (float*)spbuf;
    part[w * 256 +   0 + lane] = acc0;
    part[w * 256 +  64 + lane] = acc1;
    part[w * 256 + 128 + lane] = acc2;
    part[w * 256 + 192 + lane] = acc3;
    __syncthreads();

    float y = part[tid] + part[256 + tid] + part[512 + tid] + part[768 + tid];
    int p = pg * 256 + tid;
    bool m = mode ? (((const uint8_t*)inside)[p] != 0)
                  : (((const int*)inside)[p] != 0);
    if (m) atomicAdd(&out[p], y);   // 8 adds/point (one per seg-quad)
}

extern "C" void kernel_launch(void* const* d_in, const int* in_sizes, int n_in,
                              void* d_out, int out_size, void* d_ws, size_t ws_size,
                              hipStream_t stream) {
    const float* x        = (const float*)d_in[0];
    const float* xyz      = (const float*)d_in[1];
    const float* weight   = (const float*)d_in[2];
    const float* scaling  = (const float*)d_in[3];
    const float* rotation = (const float*)d_in[4];
    const float* values   = (const float*)d_in[5];
    const void*  inside   = d_in[6];

    float* ws  = (float*)d_ws;
    float* out = (float*)d_out;

    // 256 B header + (G_N+2)*16 floats
    if (ws_size < (size_t)(256 + (G_N + 2) * 16 * 4)) return;

    hipMemsetAsync(d_out, 0, (size_t)P_N * sizeof(float), stream);

    precompute_kernel<<<(G_N + 255) / 256, 256, 0, stream>>>(
        xyz, weight, scaling, rotation, values, (const uint8_t*)inside, ws);

    // 256 point-groups x 8 seg-quads = 2048 blocks x 4 waves = 8192 waves
    eval_kernel<<<(P_N / 256) * 8, 256, 0, stream>>>(x, ws, inside, out);
}